// Round 11
// baseline (373.210 us; speedup 1.0000x reference)
//
#include <hip/hip_runtime.h>

#define EPS 1e-6f

// Sizes (fixed): B=4, N=1024, DIM=384, H=12, d=32, BH=48
// ws layout (bytes): qw f32 [0,6MiB) | kw f32 [6,12) | op f32 [12,18) | vw [18, 18+6or12)
//   vw is f64 (12 MiB) when ws_size >= 30 MiB (f32->f64 cvt is EXACT -> bit-identical
//   numerics), else f32 (proven 24 MiB footprint).

// ---------------- Kernel 1: qkv = x @ w_qkv, relu+eps on q,k, scatter to [BH][N][32] ----------------
template <bool V64>
__global__ __launch_bounds__(256) void qkv_gemm(const float* __restrict__ x,
                                                const float* __restrict__ w,
                                                float* __restrict__ qw,
                                                float* __restrict__ kw,
                                                float* __restrict__ vwf,
                                                double* __restrict__ vwd) {
    __shared__ float As[32][68];   // transposed A tile: As[k][row]
    __shared__ float Bs[32][68];   // natural B tile:    Bs[k][col]
    const int t = threadIdx.x;
    const int m0 = blockIdx.y * 64;
    const int c0 = blockIdx.x * 64;
    const int tx = t & 15, ty = t >> 4;

    float acc[4][4];
#pragma unroll
    for (int i = 0; i < 4; i++)
#pragma unroll
        for (int j = 0; j < 4; j++) acc[i][j] = 0.f;

    for (int k0 = 0; k0 < 384; k0 += 32) {
        __syncthreads();
#pragma unroll
        for (int l = 0; l < 2; l++) {
            int idx = t * 2 + l;
            int r = idx >> 3, c4 = (idx & 7) * 4;
            float4 a = *(const float4*)(x + (size_t)(m0 + r) * 384 + k0 + c4);
            As[c4 + 0][r] = a.x;
            As[c4 + 1][r] = a.y;
            As[c4 + 2][r] = a.z;
            As[c4 + 3][r] = a.w;
        }
#pragma unroll
        for (int l = 0; l < 2; l++) {
            int idx = t * 2 + l;
            int kr = idx >> 4, cc = (idx & 15) * 4;
            *(float4*)&Bs[kr][cc] = *(const float4*)(w + (size_t)(k0 + kr) * 1152 + c0 + cc);
        }
        __syncthreads();
#pragma unroll
        for (int kk = 0; kk < 32; kk++) {
            float4 a = *(float4*)&As[kk][ty * 4];
            float4 bb = *(float4*)&Bs[kk][tx * 4];
            float av[4] = {a.x, a.y, a.z, a.w};
            float bv[4] = {bb.x, bb.y, bb.z, bb.w};
#pragma unroll
            for (int i = 0; i < 4; i++)
#pragma unroll
                for (int j = 0; j < 4; j++) acc[i][j] += av[i] * bv[j];
        }
    }
    const int sec = (c0 + tx * 4) / 384;           // 0=q, 1=k, 2=v (uniform per block)
    const int cc0 = c0 + tx * 4 - sec * 384;
    const int h = cc0 >> 5, dd = cc0 & 31;
#pragma unroll
    for (int i = 0; i < 4; i++) {
        int row = m0 + ty * 4 + i;
        int b = row >> 10, n = row & 1023;
        size_t base = (size_t)((b * 12 + h) * 1024 + n) * 32 + dd;
        if (sec < 2) {
            float* dst = (sec == 0) ? qw : kw;
            float4 o;
            o.x = fmaxf(acc[i][0], 0.f) + EPS;
            o.y = fmaxf(acc[i][1], 0.f) + EPS;
            o.z = fmaxf(acc[i][2], 0.f) + EPS;
            o.w = fmaxf(acc[i][3], 0.f) + EPS;
            *(float4*)(dst + base) = o;
        } else if (V64) {
            double2 d0 = {(double)acc[i][0], (double)acc[i][1]};
            double2 d1 = {(double)acc[i][2], (double)acc[i][3]};
            *(double2*)(vwd + base) = d0;
            *(double2*)(vwd + base + 2) = d1;
        } else {
            float4 o = make_float4(acc[i][0], acc[i][1], acc[i][2], acc[i][3]);
            *(float4*)(vwf + base) = o;
        }
    }
}

// ---------------- Kernel 2: Toeplitz-masked linear attention, LDS-free hot loop ----------------
// 512 threads = 8 waves; wave wv handles m = wv, wv+8, ... (128 iters, no barriers).
// K[m][:], V[m][:] wave-uniform -> scalar (SMEM) loads; Q row + f64 accumulators in
// registers; LDS only for Toeplitz window (conflict-free b32 broadcast) + end reduction.
// VT=double: zero cvts in the hot loop (cvt done exactly in qkv_gemm).
// f64 reduce order: within-wave m ascending (stride 8), then w0+w1+...+w7 sequential.
template <typename VT>
__global__ __launch_bounds__(512) void toep_attn(const float* __restrict__ q,
                                                 const float* __restrict__ k,
                                                 const VT* __restrict__ v,
                                                 const float* __restrict__ tw,
                                                 float* __restrict__ op) {
    const int t = threadIdx.x;
    const int r = t & 63;                                   // output row within tile
    const int wv = __builtin_amdgcn_readfirstlane(t >> 6);  // wave id 0..7, SGPR-uniform
    const int n0 = blockIdx.x * 64;
    const int bh = blockIdx.y;
    const int b = bh / 12, h = bh % 12;

    __shared__ float Tw[1088];       // tw[n0 .. n0+1086]
    __shared__ double red[64][33];   // end reduction: 32 num + den per row

    const float* qb = q + (size_t)bh * 32768;
    const float* kb = k + (size_t)bh * 32768;
    const VT*    vb = v + (size_t)bh * 32768;

    // stage Toeplitz window once: j in [0,1087), tw index n0+j <= 960+1086 = 2046 ok
    for (int j = t; j < 1087; j += 512) Tw[j] = tw[n0 + j];

    // Q row r -> 32 VGPRs
    float qr[32];
#pragma unroll
    for (int c = 0; c < 8; c++) {
        float4 f = *(const float4*)(qb + (size_t)(n0 + r) * 32 + c * 4);
        qr[c * 4 + 0] = f.x; qr[c * 4 + 1] = f.y;
        qr[c * 4 + 2] = f.z; qr[c * 4 + 3] = f.w;
    }
    __syncthreads();

    double num[32];
#pragma unroll
    for (int c = 0; c < 32; c++) num[c] = 0.0;
    double den = 0.0;

    for (int m = wv; m < 1024; m += 8) {
        const float* kr = kb + (size_t)m * 32;   // wave-uniform -> scalar loads
        const VT*    vr = vb + (size_t)m * 32;   // wave-uniform -> scalar loads
        // f32 dot, d ascending: bit-identical chain to prior rounds
        float s = 0.f;
#pragma unroll
        for (int d = 0; d < 32; d++) s += qr[d] * kr[d];
        // Toeplitz mask: local index r-m+1023 in [0,1087)
        s *= Tw[r - m + 1023];
        double sd = (double)s;
        den += sd;
#pragma unroll
        for (int c = 0; c < 32; c++) num[c] += sd * (double)vr[c];
    }

    // cross-wave reduction, deterministic order w0+w1+...+w7
    if (wv == 0) {
#pragma unroll
        for (int c = 0; c < 32; c++) red[r][c] = num[c];
        red[r][32] = den;
    }
    __syncthreads();
#pragma unroll 1
    for (int ww = 1; ww < 8; ww++) {
        if (wv == ww) {
#pragma unroll
            for (int c = 0; c < 32; c++) red[r][c] += num[c];
            red[r][32] += den;
        }
        __syncthreads();
    }

    // output: thread t -> row t>>3, cols 4*(t&7)..+3
    {
        int orow = t >> 3, cg = (t & 7) * 4;
        double inv = 1.0 / (red[orow][32] + (double)EPS);
        float4 o;
        o.x = (float)(red[orow][cg + 0] * inv);
        o.y = (float)(red[orow][cg + 1] * inv);
        o.z = (float)(red[orow][cg + 2] * inv);
        o.w = (float)(red[orow][cg + 3] * inv);
        *(float4*)(op + (size_t)(b * 1024 + n0 + orow) * 384 + h * 32 + cg) = o;
    }
}

// ---------------- Kernel 3: out = op @ w_out^T + b_out ----------------
__global__ __launch_bounds__(256) void out_gemm(const float* __restrict__ a,
                                                const float* __restrict__ w,
                                                const float* __restrict__ bias,
                                                float* __restrict__ out) {
    __shared__ float As[32][68];   // As[k][row]
    __shared__ float Bs[32][68];   // Bs[k][cout] = w[cout][k] transposed
    const int t = threadIdx.x;
    const int m0 = blockIdx.y * 64;
    const int c0 = blockIdx.x * 64;
    const int tx = t & 15, ty = t >> 4;

    float acc[4][4];
#pragma unroll
    for (int i = 0; i < 4; i++)
#pragma unroll
        for (int j = 0; j < 4; j++) acc[i][j] = 0.f;

    for (int k0 = 0; k0 < 384; k0 += 32) {
        __syncthreads();
#pragma unroll
        for (int l = 0; l < 2; l++) {
            int idx = t * 2 + l;
            int r = idx >> 3, c4 = (idx & 7) * 4;
            float4 av = *(const float4*)(a + (size_t)(m0 + r) * 384 + k0 + c4);
            As[c4 + 0][r] = av.x;
            As[c4 + 1][r] = av.y;
            As[c4 + 2][r] = av.z;
            As[c4 + 3][r] = av.w;
        }
#pragma unroll
        for (int l = 0; l < 2; l++) {
            int idx = t * 2 + l;
            int r = idx >> 3, c4 = (idx & 7) * 4;
            float4 wv = *(const float4*)(w + (size_t)(c0 + r) * 384 + k0 + c4);
            Bs[c4 + 0][r] = wv.x;
            Bs[c4 + 1][r] = wv.y;
            Bs[c4 + 2][r] = wv.z;
            Bs[c4 + 3][r] = wv.w;
        }
        __syncthreads();
#pragma unroll
        for (int kk = 0; kk < 32; kk++) {
            float4 a4 = *(float4*)&As[kk][ty * 4];
            float4 b4 = *(float4*)&Bs[kk][tx * 4];
            float av[4] = {a4.x, a4.y, a4.z, a4.w};
            float bv[4] = {b4.x, b4.y, b4.z, b4.w};
#pragma unroll
            for (int i = 0; i < 4; i++)
#pragma unroll
                for (int j = 0; j < 4; j++) acc[i][j] += av[i] * bv[j];
        }
    }
    const int col = c0 + tx * 4;
    float4 bb = *(const float4*)(bias + col);
#pragma unroll
    for (int i = 0; i < 4; i++) {
        int row = m0 + ty * 4 + i;
        float4 o = {acc[i][0] + bb.x, acc[i][1] + bb.y,
                    acc[i][2] + bb.z, acc[i][3] + bb.w};
        *(float4*)(out + (size_t)row * 384 + col) = o;
    }
}

extern "C" void kernel_launch(void* const* d_in, const int* in_sizes, int n_in,
                              void* d_out, int out_size, void* d_ws, size_t ws_size,
                              hipStream_t stream) {
    const float* x     = (const float*)d_in[0];
    const float* w_qkv = (const float*)d_in[1];
    const float* w_out = (const float*)d_in[2];
    const float* b_out = (const float*)d_in[3];
    const float* tw    = (const float*)d_in[4];
    float* out = (float*)d_out;

    char* ws = (char*)d_ws;
    float* qw = (float*)ws;                        // [0, 6 MiB)
    float* kw = (float*)(ws + 6291456);            // [6, 12 MiB)
    float* op = (float*)(ws + 12582912);           // [12, 18 MiB)
    // vw at 18 MiB: f64 (12 MiB) if ws allows, else f32 (6 MiB)
    const size_t V64_NEED = 18ull * 1024 * 1024 + 48ull * 1024 * 32 * sizeof(double);
    bool v64 = ws_size >= V64_NEED;                // constant across calls -> graph-safe

    if (v64) {
        double* vw = (double*)(ws + 18874368);
        qkv_gemm<true><<<dim3(18, 64), 256, 0, stream>>>(x, w_qkv, qw, kw, nullptr, vw);
        toep_attn<double><<<dim3(16, 48), 512, 0, stream>>>(qw, kw, vw, tw, op);
    } else {
        float* vw = (float*)(ws + 18874368);
        qkv_gemm<false><<<dim3(18, 64), 256, 0, stream>>>(x, w_qkv, qw, kw, vw, nullptr);
        toep_attn<float><<<dim3(16, 48), 512, 0, stream>>>(qw, kw, vw, tw, op);
    }
    out_gemm<<<dim3(6, 64), 256, 0, stream>>>(op, w_out, b_out, out);
}

// Round 12
// 321.565 us; speedup vs baseline: 1.1606x; 1.1606x over previous
//
#include <hip/hip_runtime.h>

#define EPS 1e-6f

// Sizes (fixed): B=4, N=1024, DIM=384, H=12, d=32, BH=48
// ws layout (floats): qw[48*1024*32] | kw[...] | vw[...] | op[4096*384]

// ---------------- Kernel 1: qkv = x @ w_qkv, relu+eps on q,k, scatter to [BH][N][32] ----------------
__global__ __launch_bounds__(256) void qkv_gemm(const float* __restrict__ x,
                                                const float* __restrict__ w,
                                                float* __restrict__ qw,
                                                float* __restrict__ kw,
                                                float* __restrict__ vw) {
    __shared__ float As[32][68];   // transposed A tile: As[k][row]
    __shared__ float Bs[32][68];   // natural B tile:    Bs[k][col]
    const int t = threadIdx.x;
    const int m0 = blockIdx.y * 64;
    const int c0 = blockIdx.x * 64;
    const int tx = t & 15, ty = t >> 4;

    float acc[4][4];
#pragma unroll
    for (int i = 0; i < 4; i++)
#pragma unroll
        for (int j = 0; j < 4; j++) acc[i][j] = 0.f;

    for (int k0 = 0; k0 < 384; k0 += 32) {
        __syncthreads();
#pragma unroll
        for (int l = 0; l < 2; l++) {
            int idx = t * 2 + l;
            int r = idx >> 3, c4 = (idx & 7) * 4;
            float4 a = *(const float4*)(x + (size_t)(m0 + r) * 384 + k0 + c4);
            As[c4 + 0][r] = a.x;
            As[c4 + 1][r] = a.y;
            As[c4 + 2][r] = a.z;
            As[c4 + 3][r] = a.w;
        }
#pragma unroll
        for (int l = 0; l < 2; l++) {
            int idx = t * 2 + l;
            int kr = idx >> 4, cc = (idx & 15) * 4;
            *(float4*)&Bs[kr][cc] = *(const float4*)(w + (size_t)(k0 + kr) * 1152 + c0 + cc);
        }
        __syncthreads();
#pragma unroll
        for (int kk = 0; kk < 32; kk++) {
            float4 a = *(float4*)&As[kk][ty * 4];
            float4 bb = *(float4*)&Bs[kk][tx * 4];
            float av[4] = {a.x, a.y, a.z, a.w};
            float bv[4] = {bb.x, bb.y, bb.z, bb.w};
#pragma unroll
            for (int i = 0; i < 4; i++)
#pragma unroll
                for (int j = 0; j < 4; j++) acc[i][j] += av[i] * bv[j];
        }
    }
    const int sec = (c0 + tx * 4) / 384;           // 0=q, 1=k, 2=v (uniform per block)
    float* dst = (sec == 0) ? qw : (sec == 1) ? kw : vw;
    const int cc0 = c0 + tx * 4 - sec * 384;
    const int h = cc0 >> 5, dd = cc0 & 31;
#pragma unroll
    for (int i = 0; i < 4; i++) {
        int row = m0 + ty * 4 + i;
        int b = row >> 10, n = row & 1023;
        float4 o;
        if (sec < 2) {
            o.x = fmaxf(acc[i][0], 0.f) + EPS;
            o.y = fmaxf(acc[i][1], 0.f) + EPS;
            o.z = fmaxf(acc[i][2], 0.f) + EPS;
            o.w = fmaxf(acc[i][3], 0.f) + EPS;
        } else {
            o = make_float4(acc[i][0], acc[i][1], acc[i][2], acc[i][3]);
        }
        *(float4*)(dst + (size_t)((b * 12 + h) * 1024 + n) * 32 + dd) = o;
    }
}

// ---------------- Kernel 2: Toeplitz-masked linear attention, LDS-free hot loop ----------------
// Clean A/B vs R10/R11: R10's proven f32-V scalar-load structure (101 MB fetch,
// VALU 67% at 3 waves/SIMD) + R11's 8-wave blocks (6 waves/SIMD capacity) WITHOUT
// R11's f64-V fetch doubling (which made it memory-latency-bound, VALU 38%).
// Wave wv handles m = wv, wv+8, ... (128 iters, no barriers in main loop).
// K[m][:], V[m][:] wave-uniform -> scalar (SMEM) loads; Q row + f64 accumulators
// in registers; LDS only for Toeplitz window + end reduction.
// Values identical to R10/R11 (cvt f32->f64 exact); reduce order = R11 (stride-8,
// w0..w7) which measured absmax 1024.0.
__global__ __launch_bounds__(512) void toep_attn(const float* __restrict__ q,
                                                 const float* __restrict__ k,
                                                 const float* __restrict__ v,
                                                 const float* __restrict__ tw,
                                                 float* __restrict__ op) {
    const int t = threadIdx.x;
    const int r = t & 63;                                   // output row within tile
    const int wv = __builtin_amdgcn_readfirstlane(t >> 6);  // wave id 0..7, SGPR-uniform
    const int n0 = blockIdx.x * 64;
    const int bh = blockIdx.y;
    const int b = bh / 12, h = bh % 12;

    __shared__ float Tw[1088];       // tw[n0 .. n0+1086]
    __shared__ double red[64][33];   // end reduction: 32 num + den per row

    const float* qb = q + (size_t)bh * 32768;
    const float* kb = k + (size_t)bh * 32768;
    const float* vb = v + (size_t)bh * 32768;

    // stage Toeplitz window once: j in [0,1087), tw index n0+j <= 960+1086 = 2046 ok
    for (int j = t; j < 1087; j += 512) Tw[j] = tw[n0 + j];

    // Q row r -> 32 VGPRs
    float qr[32];
#pragma unroll
    for (int c = 0; c < 8; c++) {
        float4 f = *(const float4*)(qb + (size_t)(n0 + r) * 32 + c * 4);
        qr[c * 4 + 0] = f.x; qr[c * 4 + 1] = f.y;
        qr[c * 4 + 2] = f.z; qr[c * 4 + 3] = f.w;
    }
    __syncthreads();

    double num[32];
#pragma unroll
    for (int c = 0; c < 32; c++) num[c] = 0.0;
    double den = 0.0;

    for (int m = wv; m < 1024; m += 8) {
        const float* kr = kb + (size_t)m * 32;   // wave-uniform -> scalar loads
        const float* vr = vb + (size_t)m * 32;   // wave-uniform -> scalar loads
        // f32 dot, d ascending: bit-identical chain to prior rounds
        float s = 0.f;
#pragma unroll
        for (int d = 0; d < 32; d++) s += qr[d] * kr[d];
        // Toeplitz mask: local index r-m+1023 in [0,1087)
        s *= Tw[r - m + 1023];
        double sd = (double)s;
        den += sd;
#pragma unroll
        for (int c = 0; c < 32; c++) num[c] += sd * (double)vr[c];
    }

    // cross-wave reduction, deterministic order w0+w1+...+w7
    if (wv == 0) {
#pragma unroll
        for (int c = 0; c < 32; c++) red[r][c] = num[c];
        red[r][32] = den;
    }
    __syncthreads();
#pragma unroll 1
    for (int ww = 1; ww < 8; ww++) {
        if (wv == ww) {
#pragma unroll
            for (int c = 0; c < 32; c++) red[r][c] += num[c];
            red[r][32] += den;
        }
        __syncthreads();
    }

    // output: thread t -> row t>>3, cols 4*(t&7)..+3
    {
        int orow = t >> 3, cg = (t & 7) * 4;
        double inv = 1.0 / (red[orow][32] + (double)EPS);
        float4 o;
        o.x = (float)(red[orow][cg + 0] * inv);
        o.y = (float)(red[orow][cg + 1] * inv);
        o.z = (float)(red[orow][cg + 2] * inv);
        o.w = (float)(red[orow][cg + 3] * inv);
        *(float4*)(op + (size_t)(b * 1024 + n0 + orow) * 384 + h * 32 + cg) = o;
    }
}

// ---------------- Kernel 3: out = op @ w_out^T + b_out ----------------
__global__ __launch_bounds__(256) void out_gemm(const float* __restrict__ a,
                                                const float* __restrict__ w,
                                                const float* __restrict__ bias,
                                                float* __restrict__ out) {
    __shared__ float As[32][68];   // As[k][row]
    __shared__ float Bs[32][68];   // Bs[k][cout] = w[cout][k] transposed
    const int t = threadIdx.x;
    const int m0 = blockIdx.y * 64;
    const int c0 = blockIdx.x * 64;
    const int tx = t & 15, ty = t >> 4;

    float acc[4][4];
#pragma unroll
    for (int i = 0; i < 4; i++)
#pragma unroll
        for (int j = 0; j < 4; j++) acc[i][j] = 0.f;

    for (int k0 = 0; k0 < 384; k0 += 32) {
        __syncthreads();
#pragma unroll
        for (int l = 0; l < 2; l++) {
            int idx = t * 2 + l;
            int r = idx >> 3, c4 = (idx & 7) * 4;
            float4 av = *(const float4*)(a + (size_t)(m0 + r) * 384 + k0 + c4);
            As[c4 + 0][r] = av.x;
            As[c4 + 1][r] = av.y;
            As[c4 + 2][r] = av.z;
            As[c4 + 3][r] = av.w;
        }
#pragma unroll
        for (int l = 0; l < 2; l++) {
            int idx = t * 2 + l;
            int r = idx >> 3, c4 = (idx & 7) * 4;
            float4 wv = *(const float4*)(w + (size_t)(c0 + r) * 384 + k0 + c4);
            Bs[c4 + 0][r] = wv.x;
            Bs[c4 + 1][r] = wv.y;
            Bs[c4 + 2][r] = wv.z;
            Bs[c4 + 3][r] = wv.w;
        }
        __syncthreads();
#pragma unroll
        for (int kk = 0; kk < 32; kk++) {
            float4 a4 = *(float4*)&As[kk][ty * 4];
            float4 b4 = *(float4*)&Bs[kk][tx * 4];
            float av[4] = {a4.x, a4.y, a4.z, a4.w};
            float bv[4] = {b4.x, b4.y, b4.z, b4.w};
#pragma unroll
            for (int i = 0; i < 4; i++)
#pragma unroll
                for (int j = 0; j < 4; j++) acc[i][j] += av[i] * bv[j];
        }
    }
    const int col = c0 + tx * 4;
    float4 bb = *(const float4*)(bias + col);
#pragma unroll
    for (int i = 0; i < 4; i++) {
        int row = m0 + ty * 4 + i;
        float4 o = {acc[i][0] + bb.x, acc[i][1] + bb.y,
                    acc[i][2] + bb.z, acc[i][3] + bb.w};
        *(float4*)(out + (size_t)row * 384 + col) = o;
    }
}

extern "C" void kernel_launch(void* const* d_in, const int* in_sizes, int n_in,
                              void* d_out, int out_size, void* d_ws, size_t ws_size,
                              hipStream_t stream) {
    const float* x     = (const float*)d_in[0];
    const float* w_qkv = (const float*)d_in[1];
    const float* w_out = (const float*)d_in[2];
    const float* b_out = (const float*)d_in[3];
    const float* tw    = (const float*)d_in[4];
    float* out = (float*)d_out;

    float* qw = (float*)d_ws;            // 48*1024*32 = 1572864 floats
    float* kw = qw + 1572864;
    float* vw = kw + 1572864;
    float* op = vw + 1572864;            // 4096*384  = 1572864 floats

    qkv_gemm<<<dim3(18, 64), 256, 0, stream>>>(x, w_qkv, qw, kw, vw);
    toep_attn<<<dim3(16, 48), 512, 0, stream>>>(qw, kw, vw, tw, op);
    out_gemm<<<dim3(6, 64), 256, 0, stream>>>(op, w_out, b_out, out);
}